// Round 1
// baseline (520.148 us; speedup 1.0000x reference)
//
#include <hip/hip_runtime.h>
#include <stdint.h>

typedef unsigned short ushort_t;
typedef __attribute__((ext_vector_type(8))) short s8v;
typedef __attribute__((ext_vector_type(4))) float f4v;

#define NH 32
#define NKV 8
#define HD 64
#define S_LEN 2048
#define HID 2048
#define DQKV 3072

__device__ __forceinline__ ushort_t f2b(float f) {
  union { float f; unsigned u; } v; v.f = f;
  unsigned r = v.u + 0x7FFFu + ((v.u >> 16) & 1u);
  return (ushort_t)(r >> 16);
}
__device__ __forceinline__ float b2f(ushort_t h) {
  union { unsigned u; float f; } v; v.u = ((unsigned)h) << 16;
  return v.f;
}

// ---------------- f32 -> bf16 convert (x4 vectorized) ----------------
__global__ void cvt_bf16(const float* __restrict__ in, ushort_t* __restrict__ out, int n4) {
  int stride = gridDim.x * blockDim.x;
  for (int i = blockIdx.x * blockDim.x + threadIdx.x; i < n4; i += stride) {
    float4 v = ((const float4*)in)[i];
    uint2 p;
    p.x = (unsigned)f2b(v.x) | ((unsigned)f2b(v.y) << 16);
    p.y = (unsigned)f2b(v.z) | ((unsigned)f2b(v.w) << 16);
    ((uint2*)out)[i] = p;
  }
}

// ---------------- GEMM: C[M,N] = A[M,K] * B[N,K]^T  (bf16 in, CT out) ----------------
// m97-style: 128x128 tile, BK=32, 4 waves (2x2 of 64x64), global_load_lds staging.
template <typename CT>
__global__ __launch_bounds__(256) void gemm_bt(
    const ushort_t* __restrict__ A, const ushort_t* __restrict__ B,
    CT* __restrict__ C, int M, int N, int K) {
  __shared__ ushort_t sA[128 * 32];
  __shared__ ushort_t sB[128 * 32];
  const int tid = threadIdx.x;
  const int wave = tid >> 6, lane = tid & 63;
  const int bm = blockIdx.y * 128, bn = blockIdx.x * 128;
  const int wm = (wave >> 1) * 64, wn = (wave & 1) * 64;
  const int srow = wave * 16 + (lane >> 2);   // staging row within 64-row chunk
  const int scol = (lane & 3) * 8;            // staging col (bf16 elems)
  const int fr = lane & 15, fg = lane >> 4;

  f4v acc[4][4];
#pragma unroll
  for (int m = 0; m < 4; ++m)
#pragma unroll
    for (int n = 0; n < 4; ++n) acc[m][n] = (f4v){0.f, 0.f, 0.f, 0.f};

  for (int k0 = 0; k0 < K; k0 += 32) {
    __syncthreads();  // previous iteration's reads done before overwrite
#pragma unroll
    for (int it = 0; it < 2; ++it) {
      int r = it * 64 + srow;
      __builtin_amdgcn_global_load_lds(
          (const __attribute__((address_space(1))) void*)(A + (size_t)(bm + r) * K + k0 + scol),
          (__attribute__((address_space(3))) void*)(&sA[(it * 64 + wave * 16) * 32]),
          16, 0, 0);
      __builtin_amdgcn_global_load_lds(
          (const __attribute__((address_space(1))) void*)(B + (size_t)(bn + r) * K + k0 + scol),
          (__attribute__((address_space(3))) void*)(&sB[(it * 64 + wave * 16) * 32]),
          16, 0, 0);
    }
    __syncthreads();  // compiler drains vmcnt before s_barrier

    s8v af[4], bf[4];
#pragma unroll
    for (int m = 0; m < 4; ++m)
      af[m] = *(const s8v*)&sA[(wm + m * 16 + fr) * 32 + fg * 8];
#pragma unroll
    for (int n = 0; n < 4; ++n)
      bf[n] = *(const s8v*)&sB[(wn + n * 16 + fr) * 32 + fg * 8];
#pragma unroll
    for (int m = 0; m < 4; ++m)
#pragma unroll
      for (int n = 0; n < 4; ++n)
        acc[m][n] = __builtin_amdgcn_mfma_f32_16x16x32_bf16(af[m], bf[n], acc[m][n], 0, 0, 0);
  }

  // epilogue: D row = (lane>>4)*4+reg, col = lane&15 (verified C/D layout)
#pragma unroll
  for (int m = 0; m < 4; ++m)
#pragma unroll
    for (int n = 0; n < 4; ++n)
#pragma unroll
      for (int rr = 0; rr < 4; ++rr) {
        int row = bm + wm + m * 16 + fg * 4 + rr;
        int col = bn + wn + n * 16 + fr;
        float v = acc[m][n][rr];
        if constexpr (sizeof(CT) == 2)
          C[(size_t)row * N + col] = (CT)f2b(v);
        else
          C[(size_t)row * N + col] = v;
      }
}

// ---------------- RoPE on q,k (reads bf16 qkv, writes scaled Q and K) ----------------
__global__ void rope_qk(const ushort_t* __restrict__ qkv, const float* __restrict__ fc,
                        ushort_t* __restrict__ Qb, ushort_t* __restrict__ Kb) {
  int tid = blockIdx.x * blockDim.x + threadIdx.x;
  if (tid >= S_LEN * 1280) return;          // (NH+NKV)*HD/2 = 1280 pairs per row
  int s = tid / 1280, c = tid - s * 1280;
  int h = c >> 5, i = c & 31;
  const ushort_t* row = qkv + (size_t)s * DQKV + h * 64 + 2 * i;
  float x0 = b2f(row[0]), x1 = b2f(row[1]);
  float cs = fc[s * 64 + 2 * i], sn = fc[s * 64 + 2 * i + 1];
  float o0 = x0 * cs - x1 * sn;
  float o1 = x1 * cs + x0 * sn;
  if (h < NH) {
    size_t o = ((size_t)s * NH + h) * 64 + 2 * i;
    Qb[o]     = f2b(o0 * 0.125f);           // fold HD^-0.5
    Qb[o + 1] = f2b(o1 * 0.125f);
  } else {
    size_t o = ((size_t)s * NKV + (h - NH)) * 64 + 2 * i;
    Kb[o]     = f2b(o0);
    Kb[o + 1] = f2b(o1);
  }
}

// ---------------- V transpose: qkv[s][2560+hd] -> Vt[hd][s] (bf16) ----------------
__global__ void transp_v(const ushort_t* __restrict__ qkv, ushort_t* __restrict__ Vt) {
  __shared__ ushort_t t[32][33];
  int hd0 = blockIdx.x * 32, s0 = blockIdx.y * 32;
#pragma unroll
  for (int k = 0; k < 4; ++k) {
    int sy = threadIdx.y + k * 8;
    t[sy][threadIdx.x] = qkv[(size_t)(s0 + sy) * DQKV + 2560 + hd0 + threadIdx.x];
  }
  __syncthreads();
#pragma unroll
  for (int k = 0; k < 4; ++k) {
    int hy = threadIdx.y + k * 8;
    Vt[(size_t)(hd0 + hy) * S_LEN + s0 + threadIdx.x] = t[threadIdx.x][hy];
  }
}

// ---------------- causal GQA flash attention ----------------
// grid (S/64, NH), 4 waves/block; wave w owns q rows [blk*64+16w, +16).
__global__ __launch_bounds__(256) void attn(
    const ushort_t* __restrict__ Q, const ushort_t* __restrict__ Kc,
    const ushort_t* __restrict__ Vt, ushort_t* __restrict__ Y) {
  __shared__ ushort_t Pl[4][16 * 64];
  const int head = blockIdx.y, kvh = head >> 2;
  const int wave = threadIdx.x >> 6, lane = threadIdx.x & 63;
  const int q0 = blockIdx.x * 64 + wave * 16;
  const int fr = lane & 15, fg = lane >> 4;
  ushort_t* P = &Pl[wave][0];

  s8v qf[2];
#pragma unroll
  for (int c = 0; c < 2; ++c)
    qf[c] = *(const s8v*)(Q + ((size_t)(q0 + fr) * NH + head) * 64 + c * 32 + fg * 8);

  float m_r[4], l_r[4];
  f4v yacc[4];
#pragma unroll
  for (int r = 0; r < 4; ++r) { m_r[r] = -3.0e38f; l_r[r] = 0.f; }
#pragma unroll
  for (int d = 0; d < 4; ++d) yacc[d] = (f4v){0.f, 0.f, 0.f, 0.f};

  const int ntiles = (q0 + 15) / 64 + 1;
  for (int t = 0; t < ntiles; ++t) {
    const int kv0 = t * 64;
    // ---- scores S[16q x 64kv] = Q*K^T (Q pre-scaled) ----
    f4v sc[4];
#pragma unroll
    for (int n = 0; n < 4; ++n) {
      f4v a = (f4v){0.f, 0.f, 0.f, 0.f};
#pragma unroll
      for (int c = 0; c < 2; ++c) {
        s8v kf = *(const s8v*)(Kc + ((size_t)(kv0 + n * 16 + fr) * NKV + kvh) * 64 + c * 32 + fg * 8);
        a = __builtin_amdgcn_mfma_f32_16x16x32_bf16(qf[c], kf, a, 0, 0, 0);
      }
      sc[n] = a;
    }
    // ---- causal mask on diagonal tile ----
    if (t == ntiles - 1) {
#pragma unroll
      for (int n = 0; n < 4; ++n)
#pragma unroll
        for (int r = 0; r < 4; ++r)
          if (kv0 + n * 16 + fr > q0 + fg * 4 + r) sc[n][r] = -1e30f;
    }
    // ---- online softmax (rows live across 16-lane groups) ----
    float mx[4], al[4], rs[4];
#pragma unroll
    for (int r = 0; r < 4; ++r)
      mx[r] = fmaxf(fmaxf(sc[0][r], sc[1][r]), fmaxf(sc[2][r], sc[3][r]));
#pragma unroll
    for (int msk = 1; msk <= 8; msk <<= 1)
#pragma unroll
      for (int r = 0; r < 4; ++r)
        mx[r] = fmaxf(mx[r], __shfl_xor(mx[r], msk));
#pragma unroll
    for (int r = 0; r < 4; ++r) {
      float mn = fmaxf(m_r[r], mx[r]);
      al[r] = __expf(m_r[r] - mn);
      m_r[r] = mn;
      rs[r] = 0.f;
    }
#pragma unroll
    for (int n = 0; n < 4; ++n)
#pragma unroll
      for (int r = 0; r < 4; ++r) {
        float p = __expf(sc[n][r] - m_r[r]);
        rs[r] += p;
        P[(fg * 4 + r) * 64 + n * 16 + fr] = f2b(p);
      }
#pragma unroll
    for (int msk = 1; msk <= 8; msk <<= 1)
#pragma unroll
      for (int r = 0; r < 4; ++r)
        rs[r] += __shfl_xor(rs[r], msk);
#pragma unroll
    for (int r = 0; r < 4; ++r) l_r[r] = l_r[r] * al[r] + rs[r];
#pragma unroll
    for (int d = 0; d < 4; ++d)
#pragma unroll
      for (int r = 0; r < 4; ++r) yacc[d][r] *= al[r];
    // ensure P writes landed before fragment reads (same-wave cross-lane)
    asm volatile("s_waitcnt lgkmcnt(0)" ::: "memory");
    // ---- y += P * V ----
#pragma unroll
    for (int d = 0; d < 4; ++d) {
#pragma unroll
      for (int c = 0; c < 2; ++c) {
        s8v pf = *(const s8v*)&P[fr * 64 + c * 32 + fg * 8];
        s8v vf = *(const s8v*)(Vt + (size_t)(kvh * 64 + d * 16 + fr) * S_LEN + kv0 + c * 32 + fg * 8);
        yacc[d] = __builtin_amdgcn_mfma_f32_16x16x32_bf16(pf, vf, yacc[d], 0, 0, 0);
      }
    }
  }
  // ---- finalize: y /= l, write bf16 Y[s][head*64+d] ----
#pragma unroll
  for (int d = 0; d < 4; ++d)
#pragma unroll
    for (int r = 0; r < 4; ++r) {
      float v = yacc[d][r] / l_r[r];
      Y[(size_t)(q0 + fg * 4 + r) * HID + head * 64 + d * 16 + fr] = f2b(v);
    }
}

// ---------------- launch ----------------
extern "C" void kernel_launch(void* const* d_in, const int* in_sizes, int n_in,
                              void* d_out, int out_size, void* d_ws, size_t ws_size,
                              hipStream_t stream) {
  const float* x    = (const float*)d_in[0];
  const float* fc   = (const float*)d_in[1];
  // d_in[2] = mask (unused; causal structure is known)
  const float* wqkv = (const float*)d_in[3];
  const float* wo   = (const float*)d_in[4];
  float* out = (float*)d_out;

  char* ws = (char*)d_ws;
  ushort_t* xb    = (ushort_t*)(ws);              // 8 MB   (reused as Y later)
  ushort_t* wqkvb = (ushort_t*)(ws + 8388608);    // 12 MB
  ushort_t* wob   = (ushort_t*)(ws + 20971520);   // 8 MB
  ushort_t* qkvb  = (ushort_t*)(ws + 29360128);   // 12 MB
  ushort_t* Qb    = (ushort_t*)(ws + 41943040);   // 8 MB
  ushort_t* Kb    = (ushort_t*)(ws + 50331648);   // 2 MB
  ushort_t* Vtb   = (ushort_t*)(ws + 52428800);   // 2 MB
  ushort_t* Yb    = xb;                           // alias: x dead after GEMM1

  cvt_bf16<<<4096, 256, 0, stream>>>(x, xb, 1048576);
  cvt_bf16<<<4096, 256, 0, stream>>>(wqkv, wqkvb, 1572864);
  cvt_bf16<<<4096, 256, 0, stream>>>(wo, wob, 1048576);

  gemm_bt<ushort_t><<<dim3(24, 16), 256, 0, stream>>>(xb, wqkvb, qkvb, 2048, 3072, 2048);

  rope_qk<<<10240, 256, 0, stream>>>(qkvb, fc, Qb, Kb);
  transp_v<<<dim3(16, 64), dim3(32, 8), 0, stream>>>(qkvb, Vtb);

  attn<<<dim3(32, 32), 256, 0, stream>>>(Qb, Kb, Vtb, Yb);

  gemm_bt<float><<<dim3(16, 16), 256, 0, stream>>>(Yb, wob, out, 2048, 2048, 2048);
}

// Round 2
// 416.239 us; speedup vs baseline: 1.2496x; 1.2496x over previous
//
#include <hip/hip_runtime.h>
#include <stdint.h>

typedef unsigned short ushort_t;
typedef __attribute__((ext_vector_type(8))) short s8v;
typedef __attribute__((ext_vector_type(4))) float f4v;

#define NH 32
#define NKV 8
#define HD 64
#define S_LEN 2048
#define HID 2048
#define DQKV 3072

__device__ __forceinline__ ushort_t f2b(float f) {
  union { float f; unsigned u; } v; v.f = f;
  unsigned r = v.u + 0x7FFFu + ((v.u >> 16) & 1u);
  return (ushort_t)(r >> 16);
}
__device__ __forceinline__ float b2f(ushort_t h) {
  union { unsigned u; float f; } v; v.u = ((unsigned)h) << 16;
  return v.f;
}

// ---------------- f32 -> bf16 convert (x4 vectorized) ----------------
__global__ void cvt_bf16(const float* __restrict__ in, ushort_t* __restrict__ out, int n4) {
  int stride = gridDim.x * blockDim.x;
  for (int i = blockIdx.x * blockDim.x + threadIdx.x; i < n4; i += stride) {
    float4 v = ((const float4*)in)[i];
    uint2 p;
    p.x = (unsigned)f2b(v.x) | ((unsigned)f2b(v.y) << 16);
    p.y = (unsigned)f2b(v.z) | ((unsigned)f2b(v.w) << 16);
    ((uint2*)out)[i] = p;
  }
}

// ---------------- GEMM: C[M,N] = A[M,K] * B[N,K]^T  (bf16 in, CT out) ----------------
// m97-style: 128x128 tile, BK=32, 4 waves (2x2 of 64x64), global_load_lds staging.
template <typename CT>
__global__ __launch_bounds__(256) void gemm_bt(
    const ushort_t* __restrict__ A, const ushort_t* __restrict__ B,
    CT* __restrict__ C, int M, int N, int K) {
  __shared__ ushort_t sA[128 * 32];
  __shared__ ushort_t sB[128 * 32];
  const int tid = threadIdx.x;
  const int wave = tid >> 6, lane = tid & 63;
  const int bm = blockIdx.y * 128, bn = blockIdx.x * 128;
  const int wm = (wave >> 1) * 64, wn = (wave & 1) * 64;
  const int srow = wave * 16 + (lane >> 2);   // staging row within 64-row chunk
  const int scol = (lane & 3) * 8;            // staging col (bf16 elems)
  const int fr = lane & 15, fg = lane >> 4;

  f4v acc[4][4];
#pragma unroll
  for (int m = 0; m < 4; ++m)
#pragma unroll
    for (int n = 0; n < 4; ++n) acc[m][n] = (f4v){0.f, 0.f, 0.f, 0.f};

  for (int k0 = 0; k0 < K; k0 += 32) {
    __syncthreads();  // previous iteration's reads done before overwrite
#pragma unroll
    for (int it = 0; it < 2; ++it) {
      int r = it * 64 + srow;
      __builtin_amdgcn_global_load_lds(
          (const __attribute__((address_space(1))) void*)(A + (size_t)(bm + r) * K + k0 + scol),
          (__attribute__((address_space(3))) void*)(&sA[(it * 64 + wave * 16) * 32]),
          16, 0, 0);
      __builtin_amdgcn_global_load_lds(
          (const __attribute__((address_space(1))) void*)(B + (size_t)(bn + r) * K + k0 + scol),
          (__attribute__((address_space(3))) void*)(&sB[(it * 64 + wave * 16) * 32]),
          16, 0, 0);
    }
    __syncthreads();  // compiler drains vmcnt before s_barrier

    s8v af[4], bf[4];
#pragma unroll
    for (int m = 0; m < 4; ++m)
      af[m] = *(const s8v*)&sA[(wm + m * 16 + fr) * 32 + fg * 8];
#pragma unroll
    for (int n = 0; n < 4; ++n)
      bf[n] = *(const s8v*)&sB[(wn + n * 16 + fr) * 32 + fg * 8];
#pragma unroll
    for (int m = 0; m < 4; ++m)
#pragma unroll
      for (int n = 0; n < 4; ++n)
        acc[m][n] = __builtin_amdgcn_mfma_f32_16x16x32_bf16(af[m], bf[n], acc[m][n], 0, 0, 0);
  }

  // epilogue: D row = (lane>>4)*4+reg, col = lane&15 (verified C/D layout)
#pragma unroll
  for (int m = 0; m < 4; ++m)
#pragma unroll
    for (int n = 0; n < 4; ++n)
#pragma unroll
      for (int rr = 0; rr < 4; ++rr) {
        int row = bm + wm + m * 16 + fg * 4 + rr;
        int col = bn + wn + n * 16 + fr;
        float v = acc[m][n][rr];
        if constexpr (sizeof(CT) == 2)
          C[(size_t)row * N + col] = (CT)f2b(v);
        else
          C[(size_t)row * N + col] = v;
      }
}

// ---------------- RoPE on q,k (reads bf16 qkv, writes scaled Q and K) ----------------
__global__ void rope_qk(const ushort_t* __restrict__ qkv, const float* __restrict__ fc,
                        ushort_t* __restrict__ Qb, ushort_t* __restrict__ Kb) {
  int tid = blockIdx.x * blockDim.x + threadIdx.x;
  if (tid >= S_LEN * 1280) return;          // (NH+NKV)*HD/2 = 1280 pairs per row
  int s = tid / 1280, c = tid - s * 1280;
  int h = c >> 5, i = c & 31;
  const ushort_t* row = qkv + (size_t)s * DQKV + h * 64 + 2 * i;
  float x0 = b2f(row[0]), x1 = b2f(row[1]);
  float cs = fc[s * 64 + 2 * i], sn = fc[s * 64 + 2 * i + 1];
  float o0 = x0 * cs - x1 * sn;
  float o1 = x1 * cs + x0 * sn;
  if (h < NH) {
    size_t o = ((size_t)s * NH + h) * 64 + 2 * i;
    Qb[o]     = f2b(o0 * 0.125f);           // fold HD^-0.5
    Qb[o + 1] = f2b(o1 * 0.125f);
  } else {
    size_t o = ((size_t)s * NKV + (h - NH)) * 64 + 2 * i;
    Kb[o]     = f2b(o0);
    Kb[o + 1] = f2b(o1);
  }
}

// ---------------- V transpose: qkv[s][2560+hd] -> Vt[hd][s] (bf16) ----------------
__global__ void transp_v(const ushort_t* __restrict__ qkv, ushort_t* __restrict__ Vt) {
  __shared__ ushort_t t[32][33];
  int hd0 = blockIdx.x * 32, s0 = blockIdx.y * 32;
#pragma unroll
  for (int k = 0; k < 4; ++k) {
    int sy = threadIdx.y + k * 8;
    t[sy][threadIdx.x] = qkv[(size_t)(s0 + sy) * DQKV + 2560 + hd0 + threadIdx.x];
  }
  __syncthreads();
#pragma unroll
  for (int k = 0; k < 4; ++k) {
    int hy = threadIdx.y + k * 8;
    Vt[(size_t)(hd0 + hy) * S_LEN + s0 + threadIdx.x] = t[threadIdx.x][hy];
  }
}

// ---------------- causal GQA flash attention ----------------
// 1 wave per block (64 thr): grid (S/16, NH). Triangular causal work means
// 4-wave blocks leave CUs tail-bound on one long block (measured Occ=11%);
// 1-wave workgroups let up to 16 independent blocks/CU mix long+short work.
__global__ __launch_bounds__(64) void attn(
    const ushort_t* __restrict__ Q, const ushort_t* __restrict__ Kc,
    const ushort_t* __restrict__ Vt, ushort_t* __restrict__ Y) {
  __shared__ ushort_t P[16 * 64];
  const int head = blockIdx.y, kvh = head >> 2;
  const int lane = threadIdx.x;
  // longest q-tiles first (dispatch order ~ascending blockIdx)
  const int q0 = (gridDim.x - 1 - blockIdx.x) * 16;
  const int fr = lane & 15, fg = lane >> 4;

  s8v qf[2];
#pragma unroll
  for (int c = 0; c < 2; ++c)
    qf[c] = *(const s8v*)(Q + ((size_t)(q0 + fr) * NH + head) * 64 + c * 32 + fg * 8);

  float m_r[4], l_r[4];
  f4v yacc[4];
#pragma unroll
  for (int r = 0; r < 4; ++r) { m_r[r] = -3.0e38f; l_r[r] = 0.f; }
#pragma unroll
  for (int d = 0; d < 4; ++d) yacc[d] = (f4v){0.f, 0.f, 0.f, 0.f};

  const int ntiles = (q0 + 15) / 64 + 1;
  for (int t = 0; t < ntiles; ++t) {
    const int kv0 = t * 64;
    // ---- scores S[16q x 64kv] = Q*K^T (Q pre-scaled) ----
    f4v sc[4];
#pragma unroll
    for (int n = 0; n < 4; ++n) {
      f4v a = (f4v){0.f, 0.f, 0.f, 0.f};
#pragma unroll
      for (int c = 0; c < 2; ++c) {
        s8v kf = *(const s8v*)(Kc + ((size_t)(kv0 + n * 16 + fr) * NKV + kvh) * 64 + c * 32 + fg * 8);
        a = __builtin_amdgcn_mfma_f32_16x16x32_bf16(qf[c], kf, a, 0, 0, 0);
      }
      sc[n] = a;
    }
    // ---- causal mask on diagonal tile ----
    if (t == ntiles - 1) {
#pragma unroll
      for (int n = 0; n < 4; ++n)
#pragma unroll
        for (int r = 0; r < 4; ++r)
          if (kv0 + n * 16 + fr > q0 + fg * 4 + r) sc[n][r] = -1e30f;
    }
    // ---- online softmax (rows live across 16-lane groups) ----
    float mx[4], al[4], rs[4];
#pragma unroll
    for (int r = 0; r < 4; ++r)
      mx[r] = fmaxf(fmaxf(sc[0][r], sc[1][r]), fmaxf(sc[2][r], sc[3][r]));
#pragma unroll
    for (int msk = 1; msk <= 8; msk <<= 1)
#pragma unroll
      for (int r = 0; r < 4; ++r)
        mx[r] = fmaxf(mx[r], __shfl_xor(mx[r], msk));
#pragma unroll
    for (int r = 0; r < 4; ++r) {
      float mn = fmaxf(m_r[r], mx[r]);
      al[r] = __expf(m_r[r] - mn);
      m_r[r] = mn;
      rs[r] = 0.f;
    }
#pragma unroll
    for (int n = 0; n < 4; ++n)
#pragma unroll
      for (int r = 0; r < 4; ++r) {
        float p = __expf(sc[n][r] - m_r[r]);
        rs[r] += p;
        P[(fg * 4 + r) * 64 + n * 16 + fr] = f2b(p);
      }
#pragma unroll
    for (int msk = 1; msk <= 8; msk <<= 1)
#pragma unroll
      for (int r = 0; r < 4; ++r)
        rs[r] += __shfl_xor(rs[r], msk);
#pragma unroll
    for (int r = 0; r < 4; ++r) l_r[r] = l_r[r] * al[r] + rs[r];
#pragma unroll
    for (int d = 0; d < 4; ++d)
#pragma unroll
      for (int r = 0; r < 4; ++r) yacc[d][r] *= al[r];
    // ensure P writes landed before fragment reads (same-wave cross-lane)
    asm volatile("s_waitcnt lgkmcnt(0)" ::: "memory");
    // ---- y += P * V ----
#pragma unroll
    for (int d = 0; d < 4; ++d) {
#pragma unroll
      for (int c = 0; c < 2; ++c) {
        s8v pf = *(const s8v*)&P[fr * 64 + c * 32 + fg * 8];
        s8v vf = *(const s8v*)(Vt + (size_t)(kvh * 64 + d * 16 + fr) * S_LEN + kv0 + c * 32 + fg * 8);
        yacc[d] = __builtin_amdgcn_mfma_f32_16x16x32_bf16(pf, vf, yacc[d], 0, 0, 0);
      }
    }
  }
  // ---- finalize: y /= l, write bf16 Y[s][head*64+d] ----
#pragma unroll
  for (int d = 0; d < 4; ++d)
#pragma unroll
    for (int r = 0; r < 4; ++r) {
      float v = yacc[d][r] / l_r[r];
      Y[(size_t)(q0 + fg * 4 + r) * HID + head * 64 + d * 16 + fr] = f2b(v);
    }
}

// ---------------- launch ----------------
extern "C" void kernel_launch(void* const* d_in, const int* in_sizes, int n_in,
                              void* d_out, int out_size, void* d_ws, size_t ws_size,
                              hipStream_t stream) {
  const float* x    = (const float*)d_in[0];
  const float* fc   = (const float*)d_in[1];
  // d_in[2] = mask (unused; causal structure is known)
  const float* wqkv = (const float*)d_in[3];
  const float* wo   = (const float*)d_in[4];
  float* out = (float*)d_out;

  char* ws = (char*)d_ws;
  ushort_t* xb    = (ushort_t*)(ws);              // 8 MB   (reused as Y later)
  ushort_t* wqkvb = (ushort_t*)(ws + 8388608);    // 12 MB
  ushort_t* wob   = (ushort_t*)(ws + 20971520);   // 8 MB
  ushort_t* qkvb  = (ushort_t*)(ws + 29360128);   // 12 MB
  ushort_t* Qb    = (ushort_t*)(ws + 41943040);   // 8 MB
  ushort_t* Kb    = (ushort_t*)(ws + 50331648);   // 2 MB
  ushort_t* Vtb   = (ushort_t*)(ws + 52428800);   // 2 MB
  ushort_t* Yb    = xb;                           // alias: x dead after GEMM1

  cvt_bf16<<<4096, 256, 0, stream>>>(x, xb, 1048576);
  cvt_bf16<<<4096, 256, 0, stream>>>(wqkv, wqkvb, 1572864);
  cvt_bf16<<<4096, 256, 0, stream>>>(wo, wob, 1048576);

  gemm_bt<ushort_t><<<dim3(24, 16), 256, 0, stream>>>(xb, wqkvb, qkvb, 2048, 3072, 2048);

  rope_qk<<<10240, 256, 0, stream>>>(qkvb, fc, Qb, Kb);
  transp_v<<<dim3(16, 64), dim3(32, 8), 0, stream>>>(qkvb, Vtb);

  attn<<<dim3(128, 32), 64, 0, stream>>>(Qb, Kb, Vtb, Yb);

  gemm_bt<float><<<dim3(16, 16), 256, 0, stream>>>(Yb, wob, out, 2048, 2048, 2048);
}

// Round 3
// 341.043 us; speedup vs baseline: 1.5252x; 1.2205x over previous
//
#include <hip/hip_runtime.h>
#include <stdint.h>

typedef unsigned short ushort_t;
typedef __attribute__((ext_vector_type(8))) short s8v;
typedef __attribute__((ext_vector_type(4))) float f4v;

#define NH 32
#define NKV 8
#define HD 64
#define S_LEN 2048
#define HID 2048
#define DQKV 3072

// 0.125 (HD^-0.5) * log2(e): softmax runs in exp2 domain
#define QSCALE 0.18033688011112042f

__device__ __forceinline__ ushort_t f2b(float f) {
  union { float f; unsigned u; } v; v.f = f;
  unsigned r = v.u + 0x7FFFu + ((v.u >> 16) & 1u);
  return (ushort_t)(r >> 16);
}
__device__ __forceinline__ float b2f(ushort_t h) {
  union { unsigned u; float f; } v; v.u = ((unsigned)h) << 16;
  return v.f;
}
__device__ __forceinline__ unsigned pkbf(float lo, float hi) {
  return ((unsigned)f2b(hi) << 16) | (unsigned)f2b(lo);
}

// ---------------- f32 -> bf16 convert (x4 vectorized) ----------------
__global__ void cvt_bf16(const float* __restrict__ in, ushort_t* __restrict__ out, int n4) {
  int stride = gridDim.x * blockDim.x;
  for (int i = blockIdx.x * blockDim.x + threadIdx.x; i < n4; i += stride) {
    float4 v = ((const float4*)in)[i];
    uint2 p;
    p.x = (unsigned)f2b(v.x) | ((unsigned)f2b(v.y) << 16);
    p.y = (unsigned)f2b(v.z) | ((unsigned)f2b(v.w) << 16);
    ((uint2*)out)[i] = p;
  }
}

// ---------------- GEMM: C[M,N] = A[M,K] * B[N,K]^T  (bf16 in, CT out) ----------------
template <typename CT>
__global__ __launch_bounds__(256) void gemm_bt(
    const ushort_t* __restrict__ A, const ushort_t* __restrict__ B,
    CT* __restrict__ C, int M, int N, int K) {
  __shared__ ushort_t sA[128 * 32];
  __shared__ ushort_t sB[128 * 32];
  const int tid = threadIdx.x;
  const int wave = tid >> 6, lane = tid & 63;
  const int bm = blockIdx.y * 128, bn = blockIdx.x * 128;
  const int wm = (wave >> 1) * 64, wn = (wave & 1) * 64;
  const int srow = wave * 16 + (lane >> 2);
  const int scol = (lane & 3) * 8;
  const int fr = lane & 15, fg = lane >> 4;

  f4v acc[4][4];
#pragma unroll
  for (int m = 0; m < 4; ++m)
#pragma unroll
    for (int n = 0; n < 4; ++n) acc[m][n] = (f4v){0.f, 0.f, 0.f, 0.f};

  for (int k0 = 0; k0 < K; k0 += 32) {
    __syncthreads();
#pragma unroll
    for (int it = 0; it < 2; ++it) {
      int r = it * 64 + srow;
      __builtin_amdgcn_global_load_lds(
          (const __attribute__((address_space(1))) void*)(A + (size_t)(bm + r) * K + k0 + scol),
          (__attribute__((address_space(3))) void*)(&sA[(it * 64 + wave * 16) * 32]),
          16, 0, 0);
      __builtin_amdgcn_global_load_lds(
          (const __attribute__((address_space(1))) void*)(B + (size_t)(bn + r) * K + k0 + scol),
          (__attribute__((address_space(3))) void*)(&sB[(it * 64 + wave * 16) * 32]),
          16, 0, 0);
    }
    __syncthreads();

    s8v af[4], bf[4];
#pragma unroll
    for (int m = 0; m < 4; ++m)
      af[m] = *(const s8v*)&sA[(wm + m * 16 + fr) * 32 + fg * 8];
#pragma unroll
    for (int n = 0; n < 4; ++n)
      bf[n] = *(const s8v*)&sB[(wn + n * 16 + fr) * 32 + fg * 8];
#pragma unroll
    for (int m = 0; m < 4; ++m)
#pragma unroll
      for (int n = 0; n < 4; ++n)
        acc[m][n] = __builtin_amdgcn_mfma_f32_16x16x32_bf16(af[m], bf[n], acc[m][n], 0, 0, 0);
  }

#pragma unroll
  for (int m = 0; m < 4; ++m)
#pragma unroll
    for (int n = 0; n < 4; ++n)
#pragma unroll
      for (int rr = 0; rr < 4; ++rr) {
        int row = bm + wm + m * 16 + fg * 4 + rr;
        int col = bn + wn + n * 16 + fr;
        float v = acc[m][n][rr];
        if constexpr (sizeof(CT) == 2)
          C[(size_t)row * N + col] = (CT)f2b(v);
        else
          C[(size_t)row * N + col] = v;
      }
}

// ---------------- RoPE on q,k (vectorized: 16 elems = 8 pairs / thread) ----------------
// Q additionally scaled by HD^-0.5 * log2e (attn softmax runs in exp2 domain).
__global__ void rope_qk(const ushort_t* __restrict__ qkv, const float* __restrict__ fc,
                        ushort_t* __restrict__ Qb, ushort_t* __restrict__ Kb) {
  int tid = blockIdx.x * blockDim.x + threadIdx.x;
  if (tid >= S_LEN * 160) return;           // (NH+NKV) heads * 4 parts
  int s = tid / 160, c = tid - s * 160;
  int h = c >> 2, part = c & 3;
  const ushort_t* src = qkv + (size_t)s * DQKV + h * 64 + part * 16;
  s8v va = *(const s8v*)src;
  s8v vb = *(const s8v*)(src + 8);
  const float* fp = fc + s * 64 + part * 16;
  float4 f0 = ((const float4*)fp)[0];
  float4 f1 = ((const float4*)fp)[1];
  float4 f2 = ((const float4*)fp)[2];
  float4 f3 = ((const float4*)fp)[3];
  float cs[8] = {f0.x, f0.z, f1.x, f1.z, f2.x, f2.z, f3.x, f3.z};
  float sn[8] = {f0.y, f0.w, f1.y, f1.w, f2.y, f2.w, f3.y, f3.w};
  const float scale = (h < NH) ? QSCALE : 1.0f;
  ushort_t ob[16];
#pragma unroll
  for (int i = 0; i < 8; ++i) {
    float x0, x1;
    if (i < 4) { x0 = b2f((ushort_t)va[2 * i]); x1 = b2f((ushort_t)va[2 * i + 1]); }
    else       { x0 = b2f((ushort_t)vb[2 * i - 8]); x1 = b2f((ushort_t)vb[2 * i - 7]); }
    float o0 = (x0 * cs[i] - x1 * sn[i]) * scale;
    float o1 = (x1 * cs[i] + x0 * sn[i]) * scale;
    ob[2 * i] = f2b(o0);
    ob[2 * i + 1] = f2b(o1);
  }
  ushort_t* dst;
  if (h < NH) dst = Qb + ((size_t)s * NH + h) * 64 + part * 16;
  else        dst = Kb + ((size_t)s * NKV + (h - NH)) * 64 + part * 16;
  *(s8v*)dst = *(const s8v*)&ob[0];
  *(s8v*)(dst + 8) = *(const s8v*)&ob[8];
}

// ---------------- V transpose: qkv[s][2560+hd] -> Vt[hd][s] (bf16) ----------------
__global__ void transp_v(const ushort_t* __restrict__ qkv, ushort_t* __restrict__ Vt) {
  __shared__ ushort_t t[32][33];
  int hd0 = blockIdx.x * 32, s0 = blockIdx.y * 32;
#pragma unroll
  for (int k = 0; k < 4; ++k) {
    int sy = threadIdx.y + k * 8;
    t[sy][threadIdx.x] = qkv[(size_t)(s0 + sy) * DQKV + 2560 + hd0 + threadIdx.x];
  }
  __syncthreads();
#pragma unroll
  for (int k = 0; k < 4; ++k) {
    int hy = threadIdx.y + k * 8;
    Vt[(size_t)(hd0 + hy) * S_LEN + s0 + threadIdx.x] = t[threadIdx.x][hy];
  }
}

// ---------------- causal GQA flash attention ----------------
// 1 wave/block; wave j handles q-tiles j and 127-j (uniform 33 kv-tiles each).
// Swapped QK^T (D = S^T[kv][q], q = lane&15) -> in-lane softmax, 2 shfls.
// K rows permuted per-mfma so post-exp P is exactly the PV A-fragment: no LDS.
__global__ __launch_bounds__(64) void attn(
    const ushort_t* __restrict__ Q, const ushort_t* __restrict__ Kc,
    const ushort_t* __restrict__ Vt, ushort_t* __restrict__ Y) {
  const int head = blockIdx.y, kvh = head >> 2;
  const int lane = threadIdx.x;
  const int fr = lane & 15, fg = lane >> 4;

#pragma unroll
  for (int half = 0; half < 2; ++half) {
    const int j = half ? (127 - (int)blockIdx.x) : (int)blockIdx.x;
    const int q0 = j * 16;

    s8v qf[2];
#pragma unroll
    for (int c = 0; c < 2; ++c)
      qf[c] = *(const s8v*)(Q + ((size_t)(q0 + fr) * NH + head) * 64 + c * 32 + fg * 8);

    float m = -3.0e38f, l = 0.f;
    f4v yacc[4];
#pragma unroll
    for (int d = 0; d < 4; ++d) yacc[d] = (f4v){0.f, 0.f, 0.f, 0.f};

    const int ntiles = q0 / 64 + 1;
    for (int t = 0; t < ntiles; ++t) {
      const int kv0 = t * 64;
      // ---- S^T[kv][q]: A = K rows (permuted), B = Q ----
      f4v sc[4];
#pragma unroll
      for (int n = 0; n < 4; ++n) {
        // permuted K row so that P lands lane-local for the PV A-fragment
        const int krow = kv0 + 32 * (n >> 1) + 8 * (fr >> 2) + 4 * (n & 1) + (fr & 3);
        f4v a = (f4v){0.f, 0.f, 0.f, 0.f};
#pragma unroll
        for (int c = 0; c < 2; ++c) {
          s8v kf = *(const s8v*)(Kc + ((size_t)krow * NKV + kvh) * 64 + c * 32 + fg * 8);
          a = __builtin_amdgcn_mfma_f32_16x16x32_bf16(kf, qf[c], a, 0, 0, 0);
        }
        sc[n] = a;
      }
      // ---- causal mask (diagonal tile only); kv(n,fg,r) = perm index ----
      if (t == ntiles - 1) {
#pragma unroll
        for (int n = 0; n < 4; ++n)
#pragma unroll
          for (int r = 0; r < 4; ++r) {
            int kv = kv0 + 32 * (n >> 1) + 8 * fg + 4 * (n & 1) + r;
            if (kv > q0 + fr) sc[n][r] = -1e30f;
          }
      }
      // ---- online softmax, exp2 domain, per-lane row state (q = fr) ----
      float pmax = sc[0][0];
#pragma unroll
      for (int n = 0; n < 4; ++n)
#pragma unroll
        for (int r = 0; r < 4; ++r) pmax = fmaxf(pmax, sc[n][r]);
      pmax = fmaxf(pmax, __shfl_xor(pmax, 16));
      pmax = fmaxf(pmax, __shfl_xor(pmax, 32));
      if (!__all(pmax <= m + 8.f)) {          // defer-max (T13), wave-uniform
        float mn = fmaxf(m, pmax);
        float al = exp2f(m - mn);
        m = mn;
        l *= al;
        float aly[4];
#pragma unroll
        for (int rr = 0; rr < 4; ++rr) aly[rr] = __shfl(al, fg * 4 + rr);
#pragma unroll
        for (int d = 0; d < 4; ++d)
#pragma unroll
          for (int rr = 0; rr < 4; ++rr) yacc[d][rr] *= aly[rr];
      }
      float rs = 0.f;
#pragma unroll
      for (int n = 0; n < 4; ++n)
#pragma unroll
        for (int r = 0; r < 4; ++r) {
          float p = exp2f(sc[n][r] - m);
          sc[n][r] = p;
          rs += p;
        }
      rs += __shfl_xor(rs, 16);
      rs += __shfl_xor(rs, 32);
      l += rs;
      // ---- pack P (lane-local!) into PV A-fragments ----
      s8v pf[2];
#pragma unroll
      for (int c = 0; c < 2; ++c) {
        unsigned w0 = pkbf(sc[2 * c][0], sc[2 * c][1]);
        unsigned w1 = pkbf(sc[2 * c][2], sc[2 * c][3]);
        unsigned w2 = pkbf(sc[2 * c + 1][0], sc[2 * c + 1][1]);
        unsigned w3 = pkbf(sc[2 * c + 1][2], sc[2 * c + 1][3]);
        unsigned wb[4] = {w0, w1, w2, w3};
        pf[c] = *(const s8v*)&wb[0];
      }
      // ---- y[q][d] += P * V ----
#pragma unroll
      for (int d = 0; d < 4; ++d) {
#pragma unroll
        for (int c = 0; c < 2; ++c) {
          s8v vf = *(const s8v*)(Vt + (size_t)(kvh * 64 + d * 16 + fr) * S_LEN + kv0 + c * 32 + fg * 8);
          yacc[d] = __builtin_amdgcn_mfma_f32_16x16x32_bf16(pf[c], vf, yacc[d], 0, 0, 0);
        }
      }
    }
    // ---- finalize: y /= l (l lives at lane q; yacc rows are q = fg*4+rr) ----
    float linv[4];
#pragma unroll
    for (int rr = 0; rr < 4; ++rr) linv[rr] = 1.f / __shfl(l, fg * 4 + rr);
#pragma unroll
    for (int d = 0; d < 4; ++d)
#pragma unroll
      for (int rr = 0; rr < 4; ++rr) {
        float v = yacc[d][rr] * linv[rr];
        Y[(size_t)(q0 + fg * 4 + rr) * HID + head * 64 + d * 16 + fr] = f2b(v);
      }
  }
}

// ---------------- launch ----------------
extern "C" void kernel_launch(void* const* d_in, const int* in_sizes, int n_in,
                              void* d_out, int out_size, void* d_ws, size_t ws_size,
                              hipStream_t stream) {
  const float* x    = (const float*)d_in[0];
  const float* fc   = (const float*)d_in[1];
  const float* wqkv = (const float*)d_in[3];
  const float* wo   = (const float*)d_in[4];
  float* out = (float*)d_out;

  char* ws = (char*)d_ws;
  ushort_t* xb    = (ushort_t*)(ws);              // 8 MB   (reused as Y later)
  ushort_t* wqkvb = (ushort_t*)(ws + 8388608);    // 12 MB
  ushort_t* wob   = (ushort_t*)(ws + 20971520);   // 8 MB
  ushort_t* qkvb  = (ushort_t*)(ws + 29360128);   // 12 MB
  ushort_t* Qb    = (ushort_t*)(ws + 41943040);   // 8 MB
  ushort_t* Kb    = (ushort_t*)(ws + 50331648);   // 2 MB
  ushort_t* Vtb   = (ushort_t*)(ws + 52428800);   // 2 MB
  ushort_t* Yb    = xb;

  cvt_bf16<<<4096, 256, 0, stream>>>(x, xb, 1048576);
  cvt_bf16<<<4096, 256, 0, stream>>>(wqkv, wqkvb, 1572864);
  cvt_bf16<<<4096, 256, 0, stream>>>(wo, wob, 1048576);

  gemm_bt<ushort_t><<<dim3(24, 16), 256, 0, stream>>>(xb, wqkvb, qkvb, 2048, 3072, 2048);

  rope_qk<<<1280, 256, 0, stream>>>(qkvb, fc, Qb, Kb);
  transp_v<<<dim3(16, 64), dim3(32, 8), 0, stream>>>(qkvb, Vtb);

  attn<<<dim3(64, 32), 64, 0, stream>>>(Qb, Kb, Vtb, Yb);

  gemm_bt<float><<<dim3(16, 16), 256, 0, stream>>>(Yb, wob, out, 2048, 2048, 2048);
}